// Round 6
// baseline (113.383 us; speedup 1.0000x reference)
//
#include <hip/hip_runtime.h>
#include <math.h>

constexpr int B_ = 4, C_ = 32, L_ = 256, M_ = 256, F_ = 8, N_ = 64;

// One (b,l) per 256-thread block (4 waves). Wave w reduces c-quarter
// [8w, 8w+8); lane covers m = 4*lane..4*lane+3 (float4 = 1 KB/instruction).
// 16 waves/CU (4/SIMD): the trajectory shows time ~ 1/waves (latency-bound),
// so this doubles TLP vs R4/R5. Acc = 8f*2*float4 = 64 floats -> fits the
// 128-VGPR cap of __launch_bounds__(256,4). Cross-wave combine: 32 KB LDS,
// two rounds. LDS total 34 KB * 4 blocks/CU = 136 <= 160 KiB.
__global__ __launch_bounds__(256, 4) void sphereconv_kernel(
    const float* __restrict__ xr, const float* __restrict__ xi,
    const float* __restrict__ wr, const float* __restrict__ wi,
    float* __restrict__ out)
{
    __shared__ float  ws[C_ * 16];        // interpolated weights [c][wr f0..7 | wi f0..7]
    __shared__ float4 red[2 * 16 * 64];   // partials from 2 waves: [src][f*2+s][lane]

    const int b    = blockIdx.x >> 8;        // / L_
    const int l    = blockIdx.x & (L_ - 1);
    const int tid  = threadIdx.x;            // 0..255
    const int wave = tid >> 6;               // c-quarter
    const int lane = tid & 63;

    // interp coords (uniform): t = l/(L-1)*(N-1)
    const float tc = ((float)l / (float)(L_ - 1)) * (float)(N_ - 1);
    int lo = (int)floorf(tc);
    if (lo > N_ - 2) lo = N_ - 2;
    const float frac = tc - (float)lo;

    // stage 512 interpolated weight floats: 2 per thread
#pragma unroll
    for (int i = tid; i < C_ * 16; i += 256) {
        const int c = i >> 4;
        const int j = i & 15;
        const int f = j & 7;
        const float* w = (j & 8) ? wi : wr;
        const int base = (f * C_ + c) * N_ + lo;   // w layout (F,C,N,1)
        ws[c * 16 + j] = w[base] * (1.0f - frac) + w[base + 1] * frac;
    }
    __syncthreads();

    const int c0 = wave * 8;
    const size_t strideC4 = (size_t)L_ * M_ / 4;   // c-stride in float4 units
    const size_t xoff = ((size_t)b * C_ + c0) * L_ * M_ + (size_t)l * M_ + lane * 4;
    const float4* xr4 = (const float4*)(xr + xoff);
    const float4* xi4 = (const float4*)(xi + xoff);

    float4 accr[F_], acci[F_];
#pragma unroll
    for (int f = 0; f < F_; ++f) {
        accr[f] = make_float4(0.f, 0.f, 0.f, 0.f);
        acci[f] = make_float4(0.f, 0.f, 0.f, 0.f);
    }

#define CX(f, A, Bv)                                          \
    accr[f].x = fmaf(A, vr.x, fmaf(-(Bv), vi.x, accr[f].x));  \
    accr[f].y = fmaf(A, vr.y, fmaf(-(Bv), vi.y, accr[f].y));  \
    accr[f].z = fmaf(A, vr.z, fmaf(-(Bv), vi.z, accr[f].z));  \
    accr[f].w = fmaf(A, vr.w, fmaf(-(Bv), vi.w, accr[f].w));  \
    acci[f].x = fmaf(A, vi.x, fmaf((Bv), vr.x, acci[f].x));   \
    acci[f].y = fmaf(A, vi.y, fmaf((Bv), vr.y, acci[f].y));   \
    acci[f].z = fmaf(A, vi.z, fmaf((Bv), vr.z, acci[f].z));   \
    acci[f].w = fmaf(A, vi.w, fmaf((Bv), vr.w, acci[f].w));

#pragma unroll
    for (int c = 0; c < 8; ++c) {
        const float4 vr = xr4[c * strideC4];
        const float4 vi = xi4[c * strideC4];
        const float* wp = &ws[(c0 + c) * 16];
        const float4 a0 = *(const float4*)(wp + 0);   // wr f0..3
        const float4 a1 = *(const float4*)(wp + 4);   // wr f4..7
        const float4 b0 = *(const float4*)(wp + 8);   // wi f0..3
        const float4 b1 = *(const float4*)(wp + 12);  // wi f4..7
        CX(0, a0.x, b0.x)
        CX(1, a0.y, b0.y)
        CX(2, a0.z, b0.z)
        CX(3, a0.w, b0.w)
        CX(4, a1.x, b1.x)
        CX(5, a1.y, b1.y)
        CX(6, a1.z, b1.z)
        CX(7, a1.w, b1.w)
    }
#undef CX

    // ---- cross-wave combine ----
    // round 1: waves 2,3 store partials
    if (wave >= 2) {
        float4* r = &red[(wave - 2) * 16 * 64];
#pragma unroll
        for (int f = 0; f < F_; ++f) {
            r[(f * 2 + 0) * 64 + lane] = accr[f];
            r[(f * 2 + 1) * 64 + lane] = acci[f];
        }
    }
    __syncthreads();
    // waves 0,1 absorb them (0<-2, 1<-3)
    if (wave < 2) {
        const float4* r = &red[wave * 16 * 64];
#pragma unroll
        for (int f = 0; f < F_; ++f) {
            const float4 pr = r[(f * 2 + 0) * 64 + lane];
            const float4 pi = r[(f * 2 + 1) * 64 + lane];
            accr[f].x += pr.x; accr[f].y += pr.y; accr[f].z += pr.z; accr[f].w += pr.w;
            acci[f].x += pi.x; acci[f].y += pi.y; acci[f].z += pi.z; acci[f].w += pi.w;
        }
    }
    __syncthreads();
    // round 2: wave 1 stores its combined partial
    if (wave == 1) {
#pragma unroll
        for (int f = 0; f < F_; ++f) {
            red[(f * 2 + 0) * 64 + lane] = accr[f];
            red[(f * 2 + 1) * 64 + lane] = acci[f];
        }
    }
    __syncthreads();
    if (wave == 0) {
        const float scale = sqrtf(1.0f + (float)l) * (1.0f / (float)C_);
        // out layout: (((s*B + b)*F + f)*L + l)*M + m ; s=0 real(relu), s=1 imag
        const size_t o0      = (((size_t)b * F_) * L_ + l) * M_ + lane * 4;
        const size_t imagOff = (size_t)B_ * F_ * L_ * M_;
        const size_t fStride = (size_t)L_ * M_;
#pragma unroll
        for (int f = 0; f < F_; ++f) {
            const float4 pr = red[(f * 2 + 0) * 64 + lane];
            const float4 pi = red[(f * 2 + 1) * 64 + lane];
            float4 yr, yi;
            yr.x = fmaxf((accr[f].x + pr.x) * scale, 0.f);
            yr.y = fmaxf((accr[f].y + pr.y) * scale, 0.f);
            yr.z = fmaxf((accr[f].z + pr.z) * scale, 0.f);
            yr.w = fmaxf((accr[f].w + pr.w) * scale, 0.f);
            yi.x = (acci[f].x + pi.x) * scale;
            yi.y = (acci[f].y + pi.y) * scale;
            yi.z = (acci[f].z + pi.z) * scale;
            yi.w = (acci[f].w + pi.w) * scale;
            *(float4*)(out + o0 + (size_t)f * fStride)           = yr;
            *(float4*)(out + o0 + (size_t)f * fStride + imagOff) = yi;
        }
    }
}

extern "C" void kernel_launch(void* const* d_in, const int* in_sizes, int n_in,
                              void* d_out, int out_size, void* d_ws, size_t ws_size,
                              hipStream_t stream) {
    const float* xr = (const float*)d_in[0];
    const float* xi = (const float*)d_in[1];
    const float* wr = (const float*)d_in[2];
    const float* wi = (const float*)d_in[3];
    float* out = (float*)d_out;
    sphereconv_kernel<<<dim3(B_ * L_), dim3(256), 0, stream>>>(xr, xi, wr, wi, out);
}